// Round 5
// baseline (406.733 us; speedup 1.0000x reference)
//
#include <hip/hip_runtime.h>
#include <stdint.h>

// SelfAttention: B=4, S=4096, D=768, causal, fp32 in/out, bf16 MFMA compute.
// cvt -> qkv GEMM -> scores GEMM (Sᵀ orientation, exp epilogue, packed causal
// P tiles) -> PV GEMM (Oᵀ orientation, /l epilogue).
// All GEMMs: 128x128 tile, BK=64 (two XOR-swizzled BK=32 panels per barrier
// pair), global_load_lds width-16, LDS = exactly 32 KB -> 5 blocks/CU.
// Output orientation chosen so the C-fragment's row dim (4 consecutive per
// lane) is the memory-contiguous dim -> direct vector stores, no LDS epilogue.
// ws layout (bf16 elements):
//   qb  12582912 @ 0           [b][s][e]
//   kb  12582912 @ 12582912    [b][s][e]
//   vt  12582912 @ 25165824    [b][e][s] (V transposed)
//   xb  12582912 @ 37748736    (dead after qkv_proj)
//   wb   1769472 @ 50331648    (dead after qkv_proj)
//   pb  34603008 @ 37748736    ALIAS over xb/wb: packed causal P tiles [q][k],
//                              tile (b, mt, nt<=mt) at slot b*528+mt(mt+1)/2+nt
//   ls  16384 fp32 @ elem 72351744
#define SEQ 4096
#define DIM 768

typedef __attribute__((ext_vector_type(8))) short short8;
typedef __attribute__((ext_vector_type(8))) unsigned short ushort8;
typedef __attribute__((ext_vector_type(4))) unsigned short ushort4v;
typedef __attribute__((ext_vector_type(4))) float fx4;
typedef unsigned short ushort;

#define MFMA16(a, b, c) __builtin_amdgcn_mfma_f32_16x16x32_bf16((a), (b), (c), 0, 0, 0)

__device__ __forceinline__ ushort f2bf(float f) {
  union { float f; unsigned int u; } v; v.f = f;
  return (ushort)((v.u + 0x7fffu + ((v.u >> 16) & 1u)) >> 16);
}
__device__ __forceinline__ float bf2f(ushort u) {
  union { unsigned int u; float f; } v; v.u = ((unsigned int)u) << 16;
  return v.f;
}
__device__ __forceinline__ void gload_lds16(const ushort* g, ushort* l) {
  __builtin_amdgcn_global_load_lds(
      (const __attribute__((address_space(1))) void*)g,
      (__attribute__((address_space(3))) void*)l, 16, 0, 0);
}

// ---------- kernel 0: fused fp32->bf16 casts + ls zero ----------
__global__ void cvt_all(const float* __restrict__ x, const float* __restrict__ wq,
                        const float* __restrict__ wk, const float* __restrict__ wv,
                        ushort* __restrict__ xb, ushort* __restrict__ wb,
                        float* __restrict__ ls) {
  const int bid = blockIdx.x;
  if (bid < 6144) {
    if (bid < 64) ls[bid * 256 + threadIdx.x] = 0.0f;
    const int i = (bid * 256 + threadIdx.x) * 8;
    fx4 a = *(const fx4*)(x + i);
    fx4 b = *(const fx4*)(x + i + 4);
    ushort8 o;
#pragma unroll
    for (int c = 0; c < 4; c++) { o[c] = f2bf(a[c]); o[c + 4] = f2bf(b[c]); }
    *(ushort8*)(xb + i) = o;
  } else {
    const int i = ((bid - 6144) * 256 + threadIdx.x) * 8;
    const int which = i / (DIM * DIM);
    const int off = i - which * (DIM * DIM);
    const float* src = (which == 0) ? wq : (which == 1) ? wk : wv;
    fx4 a = *(const fx4*)(src + off);
    fx4 b = *(const fx4*)(src + off + 4);
    ushort8 o;
#pragma unroll
    for (int c = 0; c < 4; c++) { o[c] = f2bf(a[c]); o[c + 4] = f2bf(b[c]); }
    *(ushort8*)(wb + i) = o;
  }
}

// ---------- kernel 1: QKV projection (128x128 tile, BK=64) ----------
// which<2 (Q,K): A=W (rows=e), B=x (rows=s) -> C[e][s], direct [s][e] stores.
// which==2 (V):  A=x (rows=s), B=W (rows=e) -> C[s][e], direct [e][s] stores.
__global__ __launch_bounds__(256, 5)
void qkv_proj(const ushort* __restrict__ xb, const ushort* __restrict__ wb,
              ushort* __restrict__ qb, ushort* __restrict__ kb,
              ushort* __restrict__ vt) {
  __shared__ ushort As[8192];
  __shared__ ushort Bs[8192];

  const int mb = blockIdx.x, nb = blockIdx.y;
  const int which = nb / 6;
  const int e0 = (nb % 6) * 128;
  const int s0 = mb * 128;
  const int tid = threadIdx.x;
  const int w = tid >> 6, lane = tid & 63, ln = lane & 15, quad = lane >> 4;
  const int wm = (w >> 1) * 64, wn = (w & 1) * 64;

  const ushort* W = wb + (size_t)which * (DIM * DIM);
  const ushort* Abase = (which == 2) ? xb + (size_t)s0 * DIM : W + (size_t)e0 * DIM;
  const ushort* Bbase = (which == 2) ? W + (size_t)e0 * DIM : xb + (size_t)s0 * DIM;

  // staging: chunk c -> row R=c>>2, k-group kl=(c&3)^((R>>1)&3)
  const int c0 = w * 128 + lane;
  const int c1 = c0 + 64;
  const int R0 = c0 >> 2, kl0 = (c0 & 3) ^ ((R0 >> 1) & 3);
  const int R1 = c1 >> 2, kl1 = (c1 & 3) ^ ((R1 >> 1) & 3);
  const ushort* ag0 = Abase + (size_t)R0 * DIM + kl0 * 8;
  const ushort* ag1 = Abase + (size_t)R1 * DIM + kl1 * 8;
  const ushort* bg0 = Bbase + (size_t)R0 * DIM + kl0 * 8;
  const ushort* bg1 = Bbase + (size_t)R1 * DIM + kl1 * 8;
  ushort* al0 = As + (size_t)(w * 128) * 8;
  ushort* al1 = As + (size_t)(w * 128 + 64) * 8;
  ushort* bl0 = Bs + (size_t)(w * 128) * 8;
  ushort* bl1 = Bs + (size_t)(w * 128 + 64) * 8;

  const int sw = quad ^ ((ln >> 1) & 3);
  int aoff[4], boff[4];
#pragma unroll
  for (int i = 0; i < 4; i++) aoff[i] = ((wm + i * 16 + ln) * 4 + sw) * 8;
#pragma unroll
  for (int i = 0; i < 4; i++) boff[i] = ((wn + i * 16 + ln) * 4 + sw) * 8;

  fx4 acc[4][4];
#pragma unroll
  for (int i = 0; i < 4; i++)
#pragma unroll
    for (int j = 0; j < 4; j++) acc[i][j] = (fx4)0.0f;

  for (int kk = 0; kk < DIM; kk += 64) {
    gload_lds16(ag0 + kk, al0);
    gload_lds16(ag1 + kk, al1);
    gload_lds16(ag0 + kk + 32, al0 + 4096);
    gload_lds16(ag1 + kk + 32, al1 + 4096);
    gload_lds16(bg0 + kk, bl0);
    gload_lds16(bg1 + kk, bl1);
    gload_lds16(bg0 + kk + 32, bl0 + 4096);
    gload_lds16(bg1 + kk + 32, bl1 + 4096);
    __syncthreads();
#pragma unroll
    for (int h = 0; h < 2; h++) {
      const int hb = h * 4096;
      short8 af[4], bf[4];
#pragma unroll
      for (int i = 0; i < 4; i++) af[i] = *(const short8*)(As + hb + aoff[i]);
#pragma unroll
      for (int i = 0; i < 4; i++) bf[i] = *(const short8*)(Bs + hb + boff[i]);
#pragma unroll
      for (int i = 0; i < 4; i++)
#pragma unroll
        for (int j = 0; j < 4; j++)
          acc[i][j] = MFMA16(af[i], bf[j], acc[i][j]);
    }
    __syncthreads();
  }

  if (which == 2) {
    // C[row=s][col=e]: lane holds 4 consecutive s at fixed e -> vt[e][s] 8B
#pragma unroll
    for (int i = 0; i < 4; i++)
#pragma unroll
      for (int j = 0; j < 4; j++) {
        const int s = s0 + wm + i * 16 + quad * 4;
        const int e = e0 + wn + j * 16 + ln;
        const int bb = s >> 12, si = s & 4095;
        ushort4v p;
#pragma unroll
        for (int r = 0; r < 4; r++) p[r] = f2bf(acc[i][j][r]);
        *(ushort4v*)(vt + ((size_t)bb * DIM + e) * SEQ + si) = p;
      }
  } else {
    // C[row=e][col=s]: lane holds 4 consecutive e at fixed s -> dst[s][e] 8B
    ushort* dst = (which == 0) ? qb : kb;
#pragma unroll
    for (int j = 0; j < 4; j++) {
      const int s = s0 + wn + j * 16 + ln;
#pragma unroll
      for (int i = 0; i < 4; i++) {
        ushort4v p;
#pragma unroll
        for (int r = 0; r < 4; r++) p[r] = f2bf(acc[i][j][r]);
        *(ushort4v*)(dst + (size_t)s * DIM + e0 + wm + i * 16 + quad * 4) = p;
      }
    }
  }
}

// ---------- kernel 2: scores GEMM, Sᵀ orientation (BK=64) ----------
// A=K (rows=k), B=Q (rows=q) -> C[k][q]. P[q][k] stored direct ushort4v.
__global__ __launch_bounds__(256, 5)
void attn_scores(const ushort* __restrict__ qb, const ushort* __restrict__ kb,
                 ushort* __restrict__ pb, float* __restrict__ ls) {
  __shared__ ushort As[8192];
  __shared__ ushort Bs[8192];

  const int pr = blockIdx.x;
  const int b = blockIdx.y;
  int mt = (int)(0.5f * (sqrtf(8.0f * pr + 1.0f) - 1.0f));
  while ((mt + 1) * (mt + 2) / 2 <= pr) ++mt;
  while (mt * (mt + 1) / 2 > pr) --mt;
  const int nt = pr - mt * (mt + 1) / 2;
  const int q0 = mt * 128, k0 = nt * 128;  // queries (cols), keys (rows)

  const int tid = threadIdx.x;
  const int w = tid >> 6, lane = tid & 63, ln = lane & 15, quad = lane >> 4;
  const int wm = (w >> 1) * 64, wn = (w & 1) * 64;
  const size_t qkbase = (size_t)b * SEQ * DIM;
  const float scale = 0.03608439182435161f;  // 1/sqrt(768)

  const int c0 = w * 128 + lane;
  const int c1 = c0 + 64;
  const int R0 = c0 >> 2, kl0 = (c0 & 3) ^ ((R0 >> 1) & 3);
  const int R1 = c1 >> 2, kl1 = (c1 & 3) ^ ((R1 >> 1) & 3);
  const ushort* ag0 = kb + qkbase + (size_t)(k0 + R0) * DIM + kl0 * 8;
  const ushort* ag1 = kb + qkbase + (size_t)(k0 + R1) * DIM + kl1 * 8;
  const ushort* bg0 = qb + qkbase + (size_t)(q0 + R0) * DIM + kl0 * 8;
  const ushort* bg1 = qb + qkbase + (size_t)(q0 + R1) * DIM + kl1 * 8;
  ushort* al0 = As + (size_t)(w * 128) * 8;
  ushort* al1 = As + (size_t)(w * 128 + 64) * 8;
  ushort* bl0 = Bs + (size_t)(w * 128) * 8;
  ushort* bl1 = Bs + (size_t)(w * 128 + 64) * 8;

  const int sw = quad ^ ((ln >> 1) & 3);
  int aoff[4], boff[4];
#pragma unroll
  for (int i = 0; i < 4; i++) aoff[i] = ((wm + i * 16 + ln) * 4 + sw) * 8;
#pragma unroll
  for (int i = 0; i < 4; i++) boff[i] = ((wn + i * 16 + ln) * 4 + sw) * 8;

  fx4 acc[4][4];
#pragma unroll
  for (int i = 0; i < 4; i++)
#pragma unroll
    for (int j = 0; j < 4; j++) acc[i][j] = (fx4)0.0f;

  for (int kk = 0; kk < DIM; kk += 64) {
    gload_lds16(ag0 + kk, al0);
    gload_lds16(ag1 + kk, al1);
    gload_lds16(ag0 + kk + 32, al0 + 4096);
    gload_lds16(ag1 + kk + 32, al1 + 4096);
    gload_lds16(bg0 + kk, bl0);
    gload_lds16(bg1 + kk, bl1);
    gload_lds16(bg0 + kk + 32, bl0 + 4096);
    gload_lds16(bg1 + kk + 32, bl1 + 4096);
    __syncthreads();
#pragma unroll
    for (int h = 0; h < 2; h++) {
      const int hb = h * 4096;
      short8 af[4], bf[4];
#pragma unroll
      for (int i = 0; i < 4; i++) af[i] = *(const short8*)(As + hb + aoff[i]);
#pragma unroll
      for (int i = 0; i < 4; i++) bf[i] = *(const short8*)(Bs + hb + boff[i]);
#pragma unroll
      for (int i = 0; i < 4; i++)
#pragma unroll
        for (int j = 0; j < 4; j++)
          acc[i][j] = MFMA16(af[i], bf[j], acc[i][j]);
    }
    __syncthreads();
  }

  // epilogue: C[row=k][col=q] -> exp, mask(k>q -> 0), direct P[q][k] stores,
  // row sums (over k, fixed q) via quad-shfl + 16-lane atomicAdd.
  ushort* pt = pb + ((size_t)(b * 528 + pr) << 14);
#pragma unroll
  for (int j = 0; j < 4; j++) {
    const int ql = wn + j * 16 + ln;     // local q
    const int q = q0 + ql;               // global q
    float part = 0.0f;
#pragma unroll
    for (int i = 0; i < 4; i++) {
      const int kbase = k0 + wm + i * 16 + quad * 4;  // global k of r=0
      ushort4v pk;
#pragma unroll
      for (int r = 0; r < 4; r++) {
        float p = 0.0f;
        if (kbase + r <= q) p = __expf(acc[i][j][r] * scale);
        pk[r] = f2bf(p);
        part += bf2f(pk[r]);
      }
      *(ushort4v*)(pt + ql * 128 + wm + i * 16 + quad * 4) = pk;
    }
    part += __shfl_xor(part, 16);
    part += __shfl_xor(part, 32);
    if (quad == 0) atomicAdd(ls + b * SEQ + q, part);
  }
}

// ---------- kernel 3: O = P @ V, Oᵀ orientation (BK=64, serpentine) ----------
// A=vt (rows=e), B=P (rows=q) -> C[e][q]: 4 consecutive e per lane -> fx4 store.
__global__ __launch_bounds__(256, 5)
void attn_pv(const ushort* __restrict__ pb, const ushort* __restrict__ vt,
             const float* __restrict__ ls, float* __restrict__ out) {
  __shared__ ushort As[8192];
  __shared__ ushort Bs[8192];

  // serpentine rank -> (mt desc, et, b): balances per-CU work
  int idx = blockIdx.x;
  int chunk = idx >> 8, pos = idx & 255;
  if (chunk & 1) pos = 255 - pos;
  const int r_ = (chunk << 8) + pos;
  const int mt = 31 - r_ / 24;
  const int rem = r_ % 24;
  const int b = rem & 3;
  const int et = rem >> 2;
  const int q0 = mt * 128, e0 = et * 128;

  const int tid = threadIdx.x;
  const int w = tid >> 6, lane = tid & 63, ln = lane & 15, quad = lane >> 4;
  const int wm = (w >> 1) * 64, wn = (w & 1) * 64;
  const size_t vtbase = (size_t)b * DIM * SEQ;
  const ushort* ptiles = pb + ((size_t)(b * 528 + mt * (mt + 1) / 2) << 14);

  const int c0 = w * 128 + lane;
  const int c1 = c0 + 64;
  const int R0 = c0 >> 2, kl0 = (c0 & 3) ^ ((R0 >> 1) & 3);
  const int R1 = c1 >> 2, kl1 = (c1 & 3) ^ ((R1 >> 1) & 3);
  const ushort* ag0 = vt + vtbase + (size_t)(e0 + R0) * SEQ + kl0 * 8;
  const ushort* ag1 = vt + vtbase + (size_t)(e0 + R1) * SEQ + kl1 * 8;
  const ushort* bg0 = ptiles + R0 * 128 + kl0 * 8;
  const ushort* bg1 = ptiles + R1 * 128 + kl1 * 8;
  ushort* al0 = As + (size_t)(w * 128) * 8;
  ushort* al1 = As + (size_t)(w * 128 + 64) * 8;
  ushort* bl0 = Bs + (size_t)(w * 128) * 8;
  ushort* bl1 = Bs + (size_t)(w * 128 + 64) * 8;

  const int sw = quad ^ ((ln >> 1) & 3);
  int aoff[4], boff[4];
#pragma unroll
  for (int i = 0; i < 4; i++) aoff[i] = ((wm + i * 16 + ln) * 4 + sw) * 8;
#pragma unroll
  for (int i = 0; i < 4; i++) boff[i] = ((wn + i * 16 + ln) * 4 + sw) * 8;

  fx4 acc[4][4];
#pragma unroll
  for (int i = 0; i < 4; i++)
#pragma unroll
    for (int j = 0; j < 4; j++) acc[i][j] = (fx4)0.0f;

  const int nk = (mt + 1) * 2;  // 64-wide k-steps
  for (int ks = 0; ks < nk; ks++) {
    const int ntile = ks >> 1;
    const int kin = (ks & 1) * 64;
    const size_t btile = (size_t)ntile * 16384 + kin;
    const int kglob = ntile * 128 + kin;
    gload_lds16(ag0 + kglob, al0);
    gload_lds16(ag1 + kglob, al1);
    gload_lds16(ag0 + kglob + 32, al0 + 4096);
    gload_lds16(ag1 + kglob + 32, al1 + 4096);
    gload_lds16(bg0 + btile, bl0);
    gload_lds16(bg1 + btile, bl1);
    gload_lds16(bg0 + btile + 32, bl0 + 4096);
    gload_lds16(bg1 + btile + 32, bl1 + 4096);
    __syncthreads();
#pragma unroll
    for (int h = 0; h < 2; h++) {
      const int hb = h * 4096;
      short8 af[4], bf[4];
#pragma unroll
      for (int i = 0; i < 4; i++) af[i] = *(const short8*)(As + hb + aoff[i]);
#pragma unroll
      for (int i = 0; i < 4; i++) bf[i] = *(const short8*)(Bs + hb + boff[i]);
#pragma unroll
      for (int i = 0; i < 4; i++)
#pragma unroll
        for (int j = 0; j < 4; j++)
          acc[i][j] = MFMA16(af[i], bf[j], acc[i][j]);
    }
    __syncthreads();
  }

  // epilogue: C[row=e][col=q] -> out[q][e] with 16B fx4 stores, /l
#pragma unroll
  for (int j = 0; j < 4; j++) {
    const int q = q0 + wn + j * 16 + ln;
    const float linv = 1.0f / ls[b * SEQ + q];
    float* orow = out + ((size_t)(b * SEQ + q)) * DIM + e0;
#pragma unroll
    for (int i = 0; i < 4; i++) {
      fx4 o;
#pragma unroll
      for (int r = 0; r < 4; r++) o[r] = acc[i][j][r] * linv;
      *(fx4*)(orow + wm + i * 16 + quad * 4) = o;
    }
  }
}

extern "C" void kernel_launch(void* const* d_in, const int* in_sizes, int n_in,
                              void* d_out, int out_size, void* d_ws, size_t ws_size,
                              hipStream_t stream) {
  const float* x = (const float*)d_in[0];
  const float* wq = (const float*)d_in[1];
  const float* wk = (const float*)d_in[2];
  const float* wv = (const float*)d_in[3];
  float* out = (float*)d_out;

  ushort* qb = (ushort*)d_ws;
  ushort* kb = qb + 12582912;
  ushort* vt = kb + 12582912;
  ushort* xb = vt + 12582912;
  ushort* wb = xb + 12582912;
  ushort* pb = xb;  // alias: xb/wb dead after qkv_proj
  float* ls = (float*)((ushort*)d_ws + 72351744);

  cvt_all<<<7008, 256, 0, stream>>>(x, wq, wk, wv, xb, wb, ls);
  qkv_proj<<<dim3(128, 18), 256, 0, stream>>>(xb, wb, qb, kb, vt);
  attn_scores<<<dim3(528, 4), 256, 0, stream>>>(qb, kb, pb, ls);
  attn_pv<<<768, 256, 0, stream>>>(pb, vt, ls, out);
}